// Round 5
// baseline (631.298 us; speedup 1.0000x reference)
//
#include <hip/hip_runtime.h>
#include <math.h>

#define EPS 1e-5f
constexpr int D = 64;
constexpr int BSH = 7;            // bucket shift: 128 nodes per bucket
constexpr int BW = 1 << BSH;      // 128
constexpr int MAXNB = 1024;       // supports N <= 131072
constexpr int EPT = 12;           // edges per thread (1024-thread blocks)

typedef __attribute__((ext_vector_type(8))) short bf16x8;
typedef __attribute__((ext_vector_type(4))) float f32x4;

__device__ __forceinline__ ushort f32_to_bf16_rne(float v) {
    unsigned u = __float_as_uint(v);
    return (ushort)((u + 0x7FFFu + ((u >> 16) & 1u)) >> 16);
}

// ---- A: coarse bucket histogram (LDS-binned) ----
__global__ __launch_bounds__(1024) void bucket_hist_kernel(
        const int* __restrict__ ei, int* __restrict__ gh, int E, int N, int NB) {
    __shared__ int ldsh[MAXNB];
    for (int t = threadIdx.x; t < NB; t += 1024) ldsh[t] = 0;
    __syncthreads();
    int base = blockIdx.x * (1024 * EPT);
#pragma unroll
    for (int i = 0; i < EPT; ++i) {
        int e = base + threadIdx.x + i * 1024;
        if (e < E) {
            int dst = ei[E + e];
            dst = min(max(dst, 0), N - 1);
            atomicAdd(&ldsh[dst >> BSH], 1);
        }
    }
    __syncthreads();
    for (int t = threadIdx.x; t < NB; t += 1024) {
        int c = ldsh[t];
        if (c) atomicAdd(&gh[t], c);
    }
}

// ---- B: exclusive scan of bucket counts -> bucket base + cursor ----
__global__ __launch_bounds__(1024) void bucket_scan_kernel(
        const int* __restrict__ gh, int* __restrict__ bbase,
        int* __restrict__ gcur, int NB, int E) {
    __shared__ int lds[MAXNB];
    int t = threadIdx.x;
    int v = (t < NB) ? gh[t] : 0;
    lds[t] = v;
    __syncthreads();
    for (int off = 1; off < 1024; off <<= 1) {
        int u = (t >= off) ? lds[t - off] : 0;
        __syncthreads();
        lds[t] += u;
        __syncthreads();
    }
    if (t < NB) {
        int b = lds[t] - v;        // exclusive
        bbase[t] = b;
        gcur[t] = b;
    }
    if (t == 0) bbase[NB] = E;
}

// ---- C: bin edges into bucket-contiguous regions as packed words ----
// word = (src << BSH) | (dst & (BW-1)); per-block LDS binning + run reservation
__global__ __launch_bounds__(1024) void bucket_fill_kernel(
        const int* __restrict__ ei, int* __restrict__ gcur,
        unsigned* __restrict__ pairs, int E, int N, int NB) {
    __shared__ int ldsh[MAXNB];
    for (int t = threadIdx.x; t < NB; t += 1024) ldsh[t] = 0;
    __syncthreads();
    int base = blockIdx.x * (1024 * EPT);
    int lofs[EPT];
#pragma unroll
    for (int i = 0; i < EPT; ++i) {
        int e = base + threadIdx.x + i * 1024;
        if (e < E) {
            int dst = ei[E + e];
            dst = min(max(dst, 0), N - 1);
            lofs[i] = atomicAdd(&ldsh[dst >> BSH], 1);
        }
    }
    __syncthreads();
    for (int t = threadIdx.x; t < NB; t += 1024) {
        int c = ldsh[t];
        int run = c ? atomicAdd(&gcur[t], c) : 0;
        ldsh[t] = run;             // single writer per bucket, after sync
    }
    __syncthreads();
#pragma unroll
    for (int i = 0; i < EPT; ++i) {
        int e = base + threadIdx.x + i * 1024;
        if (e < E) {
            int src = ei[e];
            int dst = ei[E + e];
            src = min(max(src, 0), N - 1);
            dst = min(max(dst, 0), N - 1);
            int b = dst >> BSH;
            unsigned w = ((unsigned)src << BSH) | (unsigned)(dst & (BW - 1));
            pairs[ldsh[b] + lofs[i]] = w;
        }
    }
}

// ---- D: per-bucket LDS-resident aggregation -> mean rows ----
// sums stride 65 breaks the stride-4 bank-coset conflict for the atomics.
__global__ __launch_bounds__(1024) void aggregate_kernel(
        const float* __restrict__ x, const unsigned* __restrict__ pairs,
        const int* __restrict__ bbase, float* __restrict__ mean_out, int N) {
    __shared__ float sums[BW * 65];
    __shared__ float cnts[BW];
    int b = blockIdx.x;
    for (int t = threadIdx.x; t < BW * 65; t += 1024) sums[t] = 0.0f;
    for (int t = threadIdx.x; t < BW; t += 1024) cnts[t] = 0.0f;
    __syncthreads();
    int e0 = bbase[b], e1 = bbase[b + 1];
    int lane = threadIdx.x & 63;
    int wv = threadIdx.x >> 6;       // wave 0..15
    int slot = lane >> 4;            // 0..3 edge slots
    int c4 = (lane & 15) << 2;       // column base
    for (int e = e0 + wv * 4 + slot; e < e1; e += 64) {
        unsigned w = pairs[e];
        int src = (int)(w >> BSH);
        int lrow = (int)(w & (BW - 1));
        float4 v = *(const float4*)&x[(size_t)src * D + c4];
        float* srow = &sums[lrow * 65 + c4];
        atomicAdd(&srow[0], v.x);
        atomicAdd(&srow[1], v.y);
        atomicAdd(&srow[2], v.z);
        atomicAdd(&srow[3], v.w);
        if ((lane & 15) == 0) atomicAdd(&cnts[lrow], 1.0f);
    }
    __syncthreads();
    int nodebase = b << BSH;
    for (int t = threadIdx.x; t < BW * D; t += 1024) {
        int lrow = t >> 6;
        int c = t & 63;
        int node = nodebase + lrow;
        if (node < N) {
            float inv = 1.0f / fmaxf(cnts[lrow], 1.0f);
            mean_out[(size_t)node * D + c] = sums[lrow * 65 + c] * inv;
        }
    }
}

// ---- pack Wl/Wr into MFMA B-fragment order, bf16 hi/lo ----
__global__ void pack_w_kernel(const float* __restrict__ Wl,
                              const float* __restrict__ Wr,
                              ushort* __restrict__ packed) {
    int t = blockIdx.x * blockDim.x + threadIdx.x;
    if (t >= 2048) return;
    int lane = t & 63;
    int frag = t >> 6;
    int kh = frag & 1;
    int ct = (frag >> 1) & 3;
    int hl = (frag >> 3) & 1;
    int mat = (frag >> 4) & 1;
    const float* W = mat ? Wr : Wl;
    int j = (lane & 15) + 16 * ct;
    int d0 = (lane >> 4) * 8 + 32 * kh;
    ushort o[8];
#pragma unroll
    for (int i = 0; i < 8; ++i) {
        float v = W[j * 64 + d0 + i];
        ushort hi = f32_to_bf16_rne(v);
        if (hl == 0) {
            o[i] = hi;
        } else {
            float r = v - __uint_as_float(((unsigned)hi) << 16);
            o[i] = f32_to_bf16_rne(r);
        }
    }
    bf16x8 w;
#pragma unroll
    for (int i = 0; i < 8; ++i) w[i] = (short)o[i];
    *(bf16x8*)&packed[(size_t)t * 8] = w;
}

// ---- MFMA linear: out = mean @ Wl^T + b + x @ Wr^T (+ stats) ----
__global__ __launch_bounds__(256, 2) void linear_mfma_kernel(
        const float* __restrict__ x, const ushort* __restrict__ packed,
        const float* __restrict__ bl, float* out, float* stats, int G, int N) {
    const int lane = threadIdx.x & 63;
    const int wid = blockIdx.x * (blockDim.x >> 6) + (threadIdx.x >> 6);
    const int nwaves = gridDim.x * (blockDim.x >> 6);
    const int r16 = lane & 15;
    const int kblk = lane >> 4;

    bf16x8 bfrag[2][2][4][2];   // [mat][hl][ct][kh]
#pragma unroll
    for (int mat = 0; mat < 2; ++mat)
#pragma unroll
        for (int hl = 0; hl < 2; ++hl)
#pragma unroll
            for (int ct = 0; ct < 4; ++ct)
#pragma unroll
                for (int kh = 0; kh < 2; ++kh) {
                    int frag = mat * 16 + hl * 8 + ct * 2 + kh;
                    bfrag[mat][hl][ct][kh] =
                        *(const bf16x8*)&packed[((size_t)frag * 64 + lane) * 8];
                }
    float blv[4];
#pragma unroll
    for (int ct = 0; ct < 4; ++ct) blv[ct] = bl[16 * ct + r16];

    float ls = 0.0f, lsq = 0.0f;
    for (int g = wid; g < G; g += nwaves) {
        int rowbase = g * 16;
        int arow = min(rowbase + r16, N - 1);
        bf16x8 ahi[2][2], alo[2][2];
#pragma unroll
        for (int mat = 0; mat < 2; ++mat) {
            const float* src = mat ? x : out;
#pragma unroll
            for (int kh = 0; kh < 2; ++kh) {
                const float* p = &src[(size_t)arow * D + kblk * 8 + kh * 32];
                float4 v0 = *(const float4*)p;
                float4 v1 = *(const float4*)(p + 4);
                float vv[8] = {v0.x, v0.y, v0.z, v0.w, v1.x, v1.y, v1.z, v1.w};
                bf16x8 h, l;
#pragma unroll
                for (int i = 0; i < 8; ++i) {
                    ushort hu = f32_to_bf16_rne(vv[i]);
                    h[i] = (short)hu;
                    float r = vv[i] - __uint_as_float(((unsigned)hu) << 16);
                    l[i] = (short)f32_to_bf16_rne(r);
                }
                ahi[mat][kh] = h;
                alo[mat][kh] = l;
            }
        }
        f32x4 acc[4];
#pragma unroll
        for (int ct = 0; ct < 4; ++ct) acc[ct] = (f32x4)(0.0f);
#pragma unroll
        for (int ct = 0; ct < 4; ++ct)
#pragma unroll
            for (int mat = 0; mat < 2; ++mat)
#pragma unroll
                for (int kh = 0; kh < 2; ++kh) {
                    acc[ct] = __builtin_amdgcn_mfma_f32_16x16x32_bf16(
                        ahi[mat][kh], bfrag[mat][0][ct][kh], acc[ct], 0, 0, 0);
                    acc[ct] = __builtin_amdgcn_mfma_f32_16x16x32_bf16(
                        ahi[mat][kh], bfrag[mat][1][ct][kh], acc[ct], 0, 0, 0);
                    acc[ct] = __builtin_amdgcn_mfma_f32_16x16x32_bf16(
                        alo[mat][kh], bfrag[mat][0][ct][kh], acc[ct], 0, 0, 0);
                }
#pragma unroll
        for (int ct = 0; ct < 4; ++ct) {
#pragma unroll
            for (int r = 0; r < 4; ++r) {
                int row = rowbase + kblk * 4 + r;
                if (row < N) {
                    float v = acc[ct][r] + blv[ct];
                    out[(size_t)row * D + 16 * ct + r16] = v;
                    ls += v;
                    lsq += v * v;
                }
            }
        }
    }
    for (int off = 32; off > 0; off >>= 1) {
        ls += __shfl_down(ls, off, 64);
        lsq += __shfl_down(lsq, off, 64);
    }
    if (lane == 0) {
        atomicAdd(&stats[0], ls);
        atomicAdd(&stats[1], lsq);
    }
}

// ---- in-place graph layernorm on d_out ----
__global__ void norm_kernel(const float* __restrict__ stats,
                            const float* __restrict__ lw,
                            const float* __restrict__ lb,
                            float* out, long long M4) {
    long long i = (long long)blockIdx.x * blockDim.x + threadIdx.x;
    if (i >= M4) return;
    const float inv_M = 1.0f / (float)(M4 * 4);
    float mu = stats[0] * inv_M;
    float var = stats[1] * inv_M - mu * mu;
    float rs = 1.0f / sqrtf(var + EPS);
    float4 v = ((const float4*)out)[i];
    int col = (int)((i * 4) & (D - 1));
    float4 w = *(const float4*)&lw[col];
    float4 b = *(const float4*)&lb[col];
    v.x = (v.x - mu) * rs * w.x + b.x;
    v.y = (v.y - mu) * rs * w.y + b.y;
    v.z = (v.z - mu) * rs * w.z + b.z;
    v.w = (v.w - mu) * rs * w.w + b.w;
    ((float4*)out)[i] = v;
}

extern "C" void kernel_launch(void* const* d_in, const int* in_sizes, int n_in,
                              void* d_out, int out_size, void* d_ws, size_t ws_size,
                              hipStream_t stream) {
    const float* x  = (const float*)d_in[0];
    const int*   ei = (const int*)d_in[1];
    const float* Wl = (const float*)d_in[2];
    const float* bl = (const float*)d_in[3];
    const float* Wr = (const float*)d_in[4];
    const float* lw = (const float*)d_in[5];
    const float* lb = (const float*)d_in[6];
    float* out = (float*)d_out;

    const int N = in_sizes[0] / D;       // 100000
    const int E = in_sizes[1] / 2;       // 1200000
    const int NB = (N + BW - 1) >> BSH;  // 782

    // ws: stats(2f) | gh(1024) | bbase(1025) | gcur(1024) | pairs(E u32) | packedw
    float* stats    = (float*)d_ws;
    int* gh         = (int*)d_ws + 2;
    int* bbase      = gh + MAXNB;
    int* gcur       = bbase + (MAXNB + 1);
    unsigned* pairs = (unsigned*)(gcur + MAXNB);
    ushort* packedw = (ushort*)(pairs + E);

    // zero stats + gh
    hipMemsetAsync(d_ws, 0, (size_t)(2 + MAXNB) * sizeof(int), stream);

    pack_w_kernel<<<8, 256, 0, stream>>>(Wl, Wr, packedw);

    int eb = (E + 1024 * EPT - 1) / (1024 * EPT);   // 98
    bucket_hist_kernel<<<eb, 1024, 0, stream>>>(ei, gh, E, N, NB);
    bucket_scan_kernel<<<1, 1024, 0, stream>>>(gh, bbase, gcur, NB, E);
    bucket_fill_kernel<<<eb, 1024, 0, stream>>>(ei, gcur, pairs, E, N, NB);

    aggregate_kernel<<<NB, 1024, 0, stream>>>(x, pairs, bbase, out, N);

    int G = (N + 15) / 16;   // 6250
    linear_mfma_kernel<<<512, 256, 0, stream>>>(x, packedw, bl, out, stats, G, N);

    long long M4 = (long long)N * D / 4;
    int blocks4 = (int)((M4 + 255) / 256);
    norm_kernel<<<blocks4, 256, 0, stream>>>(stats, lw, lb, out, M4);
}

// Round 6
// 196.225 us; speedup vs baseline: 3.2172x; 3.2172x over previous
//
#include <hip/hip_runtime.h>
#include <math.h>

#define EPS 1e-5f
constexpr int D = 64;
constexpr int BSH = 7;            // bucket shift: 128 nodes per bucket
constexpr int BW = 1 << BSH;      // 128
constexpr int MAXNB = 1024;       // supports N <= 131072
constexpr int EPT = 12;           // edges per thread (1024-thread blocks)
constexpr int CAP = 4096;         // aggregate chunk capacity (edges)

typedef __attribute__((ext_vector_type(8))) short bf16x8;
typedef __attribute__((ext_vector_type(8))) ushort ushort8;
typedef __attribute__((ext_vector_type(4))) float f32x4;

__device__ __forceinline__ ushort f32_to_bf16_rne(float v) {
    unsigned u = __float_as_uint(v);
    return (ushort)((u + 0x7FFFu + ((u >> 16) & 1u)) >> 16);
}
__device__ __forceinline__ float bf16_to_f32(ushort h) {
    return __uint_as_float(((unsigned)h) << 16);
}

// ---- x -> bf16 conversion ----
__global__ void xconv_kernel(const float* __restrict__ x,
                             ushort* __restrict__ xh, long long M8) {
    long long i = (long long)blockIdx.x * blockDim.x + threadIdx.x;
    if (i >= M8) return;
    float4 v0 = ((const float4*)x)[i * 2];
    float4 v1 = ((const float4*)x)[i * 2 + 1];
    ushort8 h;
    h[0] = f32_to_bf16_rne(v0.x); h[1] = f32_to_bf16_rne(v0.y);
    h[2] = f32_to_bf16_rne(v0.z); h[3] = f32_to_bf16_rne(v0.w);
    h[4] = f32_to_bf16_rne(v1.x); h[5] = f32_to_bf16_rne(v1.y);
    h[6] = f32_to_bf16_rne(v1.z); h[7] = f32_to_bf16_rne(v1.w);
    *(ushort8*)&xh[i * 8] = h;
}

// ---- A: coarse bucket histogram (LDS-binned) ----
__global__ __launch_bounds__(1024) void bucket_hist_kernel(
        const int* __restrict__ ei, int* __restrict__ gh, int E, int N, int NB) {
    __shared__ int ldsh[MAXNB];
    for (int t = threadIdx.x; t < NB; t += 1024) ldsh[t] = 0;
    __syncthreads();
    int base = blockIdx.x * (1024 * EPT);
#pragma unroll
    for (int i = 0; i < EPT; ++i) {
        int e = base + threadIdx.x + i * 1024;
        if (e < E) {
            int dst = ei[E + e];
            dst = min(max(dst, 0), N - 1);
            atomicAdd(&ldsh[dst >> BSH], 1);
        }
    }
    __syncthreads();
    for (int t = threadIdx.x; t < NB; t += 1024) {
        int c = ldsh[t];
        if (c) atomicAdd(&gh[t], c);
    }
}

// ---- B: exclusive scan of bucket counts -> bucket base + cursor ----
__global__ __launch_bounds__(1024) void bucket_scan_kernel(
        const int* __restrict__ gh, int* __restrict__ bbase,
        int* __restrict__ gcur, int NB, int E) {
    __shared__ int lds[MAXNB];
    int t = threadIdx.x;
    int v = (t < NB) ? gh[t] : 0;
    lds[t] = v;
    __syncthreads();
    for (int off = 1; off < 1024; off <<= 1) {
        int u = (t >= off) ? lds[t - off] : 0;
        __syncthreads();
        lds[t] += u;
        __syncthreads();
    }
    if (t < NB) {
        int b = lds[t] - v;        // exclusive
        bbase[t] = b;
        gcur[t] = b;
    }
    if (t == 0) bbase[NB] = E;
}

// ---- C: bin edges into bucket-contiguous regions as packed words ----
__global__ __launch_bounds__(1024) void bucket_fill_kernel(
        const int* __restrict__ ei, int* __restrict__ gcur,
        unsigned* __restrict__ pairs, int E, int N, int NB) {
    __shared__ int ldsh[MAXNB];
    for (int t = threadIdx.x; t < NB; t += 1024) ldsh[t] = 0;
    __syncthreads();
    int base = blockIdx.x * (1024 * EPT);
    int lofs[EPT];
#pragma unroll
    for (int i = 0; i < EPT; ++i) {
        int e = base + threadIdx.x + i * 1024;
        if (e < E) {
            int dst = ei[E + e];
            dst = min(max(dst, 0), N - 1);
            lofs[i] = atomicAdd(&ldsh[dst >> BSH], 1);
        }
    }
    __syncthreads();
    for (int t = threadIdx.x; t < NB; t += 1024) {
        int c = ldsh[t];
        int run = c ? atomicAdd(&gcur[t], c) : 0;
        ldsh[t] = run;
    }
    __syncthreads();
#pragma unroll
    for (int i = 0; i < EPT; ++i) {
        int e = base + threadIdx.x + i * 1024;
        if (e < E) {
            int src = ei[e];
            int dst = ei[E + e];
            src = min(max(src, 0), N - 1);
            dst = min(max(dst, 0), N - 1);
            int b = dst >> BSH;
            unsigned w = ((unsigned)src << BSH) | (unsigned)(dst & (BW - 1));
            pairs[ldsh[b] + lofs[i]] = w;
        }
    }
}

// ---- D: per-bucket sort-in-LDS + register gather-accumulate (no fp32 atomics)
// 16 waves; wave w owns nodes lrow = w + 16k (k=0..7); lane = 4 edge-slots x
// 16 col-quads; acc in VGPRs; bf16 x rows (128 B each).
__global__ __launch_bounds__(1024) void aggregate_kernel(
        const ushort* __restrict__ xh, const unsigned* __restrict__ pairs,
        const int* __restrict__ bbase, float* __restrict__ mean_out, int N) {
    __shared__ int cnt[BW + 1];
    __shared__ int noff[BW + 1];
    __shared__ int srcl[CAP];
    const int b = blockIdx.x;
    const int tid = threadIdx.x;
    const int lane = tid & 63;
    const int wv = tid >> 6;          // 0..15
    const int slot = lane >> 4;       // 0..3
    const int l16 = lane & 15;
    const int e0 = bbase[b], e1 = bbase[b + 1];

    float4 acc[8];
    int degt[8];
#pragma unroll
    for (int k = 0; k < 8; ++k) {
        acc[k] = make_float4(0.f, 0.f, 0.f, 0.f);
        degt[k] = 0;
    }

    for (int c0 = e0; c0 < e1; c0 += CAP) {
        int C = min(CAP, e1 - c0);
        if (tid < BW + 1) cnt[tid] = 0;
        __syncthreads();
        // pass 1: per-node count
        for (int i = tid; i < C; i += 1024)
            atomicAdd(&cnt[pairs[c0 + i] & (BW - 1)], 1);
        __syncthreads();
        // scan 128 counters (wave 0)
        if (wv == 0) {
            int c_lo = cnt[lane], c_hi = cnt[64 + lane];
            int a0 = c_lo, a1 = c_hi;
            for (int off = 1; off < 64; off <<= 1) {
                int u = __shfl_up(a0, off, 64);
                if (lane >= off) a0 += u;
            }
            for (int off = 1; off < 64; off <<= 1) {
                int u = __shfl_up(a1, off, 64);
                if (lane >= off) a1 += u;
            }
            int t0 = __shfl(a0, 63, 64);
            noff[lane] = a0 - c_lo;
            noff[64 + lane] = t0 + a1 - c_hi;
            if (lane == 63) noff[128] = t0 + a1;
        }
        __syncthreads();
        if (tid < BW) cnt[tid] = 0;
        __syncthreads();
        // pass 2: scatter src into node-sorted LDS order
        for (int i = tid; i < C; i += 1024) {
            unsigned w = pairs[c0 + i];
            int lr = (int)(w & (BW - 1));
            int p = noff[lr] + atomicAdd(&cnt[lr], 1);
            srcl[p] = (int)(w >> BSH);
        }
        __syncthreads();
        // pass 3: gather + accumulate in registers
#pragma unroll
        for (int k = 0; k < 8; ++k) {
            int lr = wv + 16 * k;
            int r0 = noff[lr], r1 = noff[lr + 1];
            degt[k] += r1 - r0;
            for (int e = r0 + slot; e < r1; e += 4) {
                int src = srcl[e];
                ushort4 h = *(const ushort4*)&xh[(size_t)src * D + l16 * 4];
                acc[k].x += bf16_to_f32(h.x);
                acc[k].y += bf16_to_f32(h.y);
                acc[k].z += bf16_to_f32(h.z);
                acc[k].w += bf16_to_f32(h.w);
            }
        }
        __syncthreads();
    }
    // reduce across the 4 edge-slots, write mean
    const int nodebase = b << BSH;
#pragma unroll
    for (int k = 0; k < 8; ++k) {
        acc[k].x += __shfl_xor(acc[k].x, 16, 64);
        acc[k].y += __shfl_xor(acc[k].y, 16, 64);
        acc[k].z += __shfl_xor(acc[k].z, 16, 64);
        acc[k].w += __shfl_xor(acc[k].w, 16, 64);
        acc[k].x += __shfl_xor(acc[k].x, 32, 64);
        acc[k].y += __shfl_xor(acc[k].y, 32, 64);
        acc[k].z += __shfl_xor(acc[k].z, 32, 64);
        acc[k].w += __shfl_xor(acc[k].w, 32, 64);
        if (slot == 0) {
            int node = nodebase + wv + 16 * k;
            if (node < N) {
                float inv = 1.0f / fmaxf((float)degt[k], 1.0f);
                float4 m;
                m.x = acc[k].x * inv; m.y = acc[k].y * inv;
                m.z = acc[k].z * inv; m.w = acc[k].w * inv;
                *(float4*)&mean_out[(size_t)node * D + l16 * 4] = m;
            }
        }
    }
}

// ---- pack Wl/Wr into MFMA B-fragment order, bf16 hi/lo ----
__global__ void pack_w_kernel(const float* __restrict__ Wl,
                              const float* __restrict__ Wr,
                              ushort* __restrict__ packed) {
    int t = blockIdx.x * blockDim.x + threadIdx.x;
    if (t >= 2048) return;
    int lane = t & 63;
    int frag = t >> 6;
    int kh = frag & 1;
    int ct = (frag >> 1) & 3;
    int hl = (frag >> 3) & 1;
    int mat = (frag >> 4) & 1;
    const float* W = mat ? Wr : Wl;
    int j = (lane & 15) + 16 * ct;
    int d0 = (lane >> 4) * 8 + 32 * kh;
    ushort o[8];
#pragma unroll
    for (int i = 0; i < 8; ++i) {
        float v = W[j * 64 + d0 + i];
        ushort hi = f32_to_bf16_rne(v);
        if (hl == 0) {
            o[i] = hi;
        } else {
            float r = v - __uint_as_float(((unsigned)hi) << 16);
            o[i] = f32_to_bf16_rne(r);
        }
    }
    bf16x8 w;
#pragma unroll
    for (int i = 0; i < 8; ++i) w[i] = (short)o[i];
    *(bf16x8*)&packed[(size_t)t * 8] = w;
}

// ---- MFMA linear: out = mean @ Wl^T + b + x @ Wr^T (+ stats) ----
__global__ __launch_bounds__(256, 2) void linear_mfma_kernel(
        const float* __restrict__ x, const ushort* __restrict__ packed,
        const float* __restrict__ bl, float* out, float* stats, int G, int N) {
    const int lane = threadIdx.x & 63;
    const int wid = blockIdx.x * (blockDim.x >> 6) + (threadIdx.x >> 6);
    const int nwaves = gridDim.x * (blockDim.x >> 6);
    const int r16 = lane & 15;
    const int kblk = lane >> 4;

    bf16x8 bfrag[2][2][4][2];   // [mat][hl][ct][kh]
#pragma unroll
    for (int mat = 0; mat < 2; ++mat)
#pragma unroll
        for (int hl = 0; hl < 2; ++hl)
#pragma unroll
            for (int ct = 0; ct < 4; ++ct)
#pragma unroll
                for (int kh = 0; kh < 2; ++kh) {
                    int frag = mat * 16 + hl * 8 + ct * 2 + kh;
                    bfrag[mat][hl][ct][kh] =
                        *(const bf16x8*)&packed[((size_t)frag * 64 + lane) * 8];
                }
    float blv[4];
#pragma unroll
    for (int ct = 0; ct < 4; ++ct) blv[ct] = bl[16 * ct + r16];

    float ls = 0.0f, lsq = 0.0f;
    for (int g = wid; g < G; g += nwaves) {
        int rowbase = g * 16;
        int arow = min(rowbase + r16, N - 1);
        bf16x8 ahi[2][2], alo[2][2];
#pragma unroll
        for (int mat = 0; mat < 2; ++mat) {
            const float* src = mat ? x : out;
#pragma unroll
            for (int kh = 0; kh < 2; ++kh) {
                const float* p = &src[(size_t)arow * D + kblk * 8 + kh * 32];
                float4 v0 = *(const float4*)p;
                float4 v1 = *(const float4*)(p + 4);
                float vv[8] = {v0.x, v0.y, v0.z, v0.w, v1.x, v1.y, v1.z, v1.w};
                bf16x8 h, l;
#pragma unroll
                for (int i = 0; i < 8; ++i) {
                    ushort hu = f32_to_bf16_rne(vv[i]);
                    h[i] = (short)hu;
                    float r = vv[i] - __uint_as_float(((unsigned)hu) << 16);
                    l[i] = (short)f32_to_bf16_rne(r);
                }
                ahi[mat][kh] = h;
                alo[mat][kh] = l;
            }
        }
        f32x4 acc[4];
#pragma unroll
        for (int ct = 0; ct < 4; ++ct) acc[ct] = (f32x4)(0.0f);
#pragma unroll
        for (int ct = 0; ct < 4; ++ct)
#pragma unroll
            for (int mat = 0; mat < 2; ++mat)
#pragma unroll
                for (int kh = 0; kh < 2; ++kh) {
                    acc[ct] = __builtin_amdgcn_mfma_f32_16x16x32_bf16(
                        ahi[mat][kh], bfrag[mat][0][ct][kh], acc[ct], 0, 0, 0);
                    acc[ct] = __builtin_amdgcn_mfma_f32_16x16x32_bf16(
                        ahi[mat][kh], bfrag[mat][1][ct][kh], acc[ct], 0, 0, 0);
                    acc[ct] = __builtin_amdgcn_mfma_f32_16x16x32_bf16(
                        alo[mat][kh], bfrag[mat][0][ct][kh], acc[ct], 0, 0, 0);
                }
#pragma unroll
        for (int ct = 0; ct < 4; ++ct) {
#pragma unroll
            for (int r = 0; r < 4; ++r) {
                int row = rowbase + kblk * 4 + r;
                if (row < N) {
                    float v = acc[ct][r] + blv[ct];
                    out[(size_t)row * D + 16 * ct + r16] = v;
                    ls += v;
                    lsq += v * v;
                }
            }
        }
    }
    for (int off = 32; off > 0; off >>= 1) {
        ls += __shfl_down(ls, off, 64);
        lsq += __shfl_down(lsq, off, 64);
    }
    if (lane == 0) {
        atomicAdd(&stats[0], ls);
        atomicAdd(&stats[1], lsq);
    }
}

// ---- in-place graph layernorm on d_out ----
__global__ void norm_kernel(const float* __restrict__ stats,
                            const float* __restrict__ lw,
                            const float* __restrict__ lb,
                            float* out, long long M4) {
    long long i = (long long)blockIdx.x * blockDim.x + threadIdx.x;
    if (i >= M4) return;
    const float inv_M = 1.0f / (float)(M4 * 4);
    float mu = stats[0] * inv_M;
    float var = stats[1] * inv_M - mu * mu;
    float rs = 1.0f / sqrtf(var + EPS);
    float4 v = ((const float4*)out)[i];
    int col = (int)((i * 4) & (D - 1));
    float4 w = *(const float4*)&lw[col];
    float4 b = *(const float4*)&lb[col];
    v.x = (v.x - mu) * rs * w.x + b.x;
    v.y = (v.y - mu) * rs * w.y + b.y;
    v.z = (v.z - mu) * rs * w.z + b.z;
    v.w = (v.w - mu) * rs * w.w + b.w;
    ((float4*)out)[i] = v;
}

extern "C" void kernel_launch(void* const* d_in, const int* in_sizes, int n_in,
                              void* d_out, int out_size, void* d_ws, size_t ws_size,
                              hipStream_t stream) {
    const float* x  = (const float*)d_in[0];
    const int*   ei = (const int*)d_in[1];
    const float* Wl = (const float*)d_in[2];
    const float* bl = (const float*)d_in[3];
    const float* Wr = (const float*)d_in[4];
    const float* lw = (const float*)d_in[5];
    const float* lb = (const float*)d_in[6];
    float* out = (float*)d_out;

    const int N = in_sizes[0] / D;       // 100000
    const int E = in_sizes[1] / 2;       // 1200000
    const int NB = (N + BW - 1) >> BSH;  // 782

    // ws: stats(2f) | gh(1024) | bbase(1025) | gcur(1024) | pairs(E u32) |
    //     packedw(2048*8 u16) | xh(N*64 u16)
    float* stats    = (float*)d_ws;
    int* gh         = (int*)d_ws + 2;
    int* bbase      = gh + MAXNB;
    int* gcur       = bbase + (MAXNB + 1);
    unsigned* pairs = (unsigned*)(gcur + MAXNB);
    ushort* packedw = (ushort*)(pairs + E);
    ushort* xh      = packedw + 2048 * 8;

    hipMemsetAsync(d_ws, 0, (size_t)(2 + MAXNB) * sizeof(int), stream);

    pack_w_kernel<<<8, 256, 0, stream>>>(Wl, Wr, packedw);

    long long M8 = (long long)N * D / 8;
    xconv_kernel<<<(int)((M8 + 255) / 256), 256, 0, stream>>>(x, xh, M8);

    int eb = (E + 1024 * EPT - 1) / (1024 * EPT);   // 98
    bucket_hist_kernel<<<eb, 1024, 0, stream>>>(ei, gh, E, N, NB);
    bucket_scan_kernel<<<1, 1024, 0, stream>>>(gh, bbase, gcur, NB, E);
    bucket_fill_kernel<<<eb, 1024, 0, stream>>>(ei, gcur, pairs, E, N, NB);

    aggregate_kernel<<<NB, 1024, 0, stream>>>(xh, pairs, bbase, out, N);

    int G = (N + 15) / 16;   // 6250
    linear_mfma_kernel<<<512, 256, 0, stream>>>(x, packedw, bl, out, stats, G, N);

    long long M4 = (long long)N * D / 4;
    int blocks4 = (int)((M4 + 255) / 256);
    norm_kernel<<<blocks4, 256, 0, stream>>>(stats, lw, lb, out, M4);
}

// Round 7
// 184.648 us; speedup vs baseline: 3.4189x; 1.0627x over previous
//
#include <hip/hip_runtime.h>
#include <math.h>

#define EPS 1e-5f
constexpr int D = 64;
constexpr int BSH = 7;            // bucket shift: 128 nodes per bucket
constexpr int BW = 1 << BSH;      // 128
constexpr int MAXNB = 1024;       // supports N <= 131072
constexpr int EPT = 12;           // edges per thread (fill, 1024-thread blocks)
constexpr int EPT_H = 16;         // edges per thread (hist, 256-thread blocks)
constexpr int AGG_WIN = 2048;     // bucket-edge window staged in LDS
constexpr int NPB = 32;           // nodes per aggregate block

typedef __attribute__((ext_vector_type(8))) short bf16x8;
typedef __attribute__((ext_vector_type(8))) ushort ushort8;
typedef __attribute__((ext_vector_type(4))) float f32x4;

__device__ __forceinline__ ushort f32_to_bf16_rne(float v) {
    unsigned u = __float_as_uint(v);
    return (ushort)((u + 0x7FFFu + ((u >> 16) & 1u)) >> 16);
}
__device__ __forceinline__ float bf16_to_f32(ushort h) {
    return __uint_as_float(((unsigned)h) << 16);
}

// ---- K1: fused prep = hist (blocks [0,hb)) | pack_w ([hb,hb+8)) | xconv ----
__global__ __launch_bounds__(256) void prep_kernel(
        const float* __restrict__ x, ushort* __restrict__ xh, long long M8,
        const int* __restrict__ ei, int* __restrict__ gh, int E, int N, int NB,
        int hb, const float* __restrict__ Wl, const float* __restrict__ Wr,
        ushort* __restrict__ packed) {
    __shared__ int ldsh[MAXNB];
    int bid = blockIdx.x;
    if (bid < hb) {
        // ---- coarse bucket histogram ----
        for (int t = threadIdx.x; t < NB; t += 256) ldsh[t] = 0;
        __syncthreads();
        int base = bid * (256 * EPT_H);
#pragma unroll
        for (int i = 0; i < EPT_H; ++i) {
            int e = base + threadIdx.x + i * 256;
            if (e < E) {
                int dst = ei[E + e];
                dst = min(max(dst, 0), N - 1);
                atomicAdd(&ldsh[dst >> BSH], 1);
            }
        }
        __syncthreads();
        for (int t = threadIdx.x; t < NB; t += 256) {
            int c = ldsh[t];
            if (c) atomicAdd(&gh[t], c);
        }
    } else if (bid < hb + 8) {
        // ---- pack Wl/Wr into MFMA B-fragment order, bf16 hi/lo ----
        int t = (bid - hb) * 256 + threadIdx.x;
        int lane = t & 63;
        int frag = t >> 6;
        int kh = frag & 1;
        int ct = (frag >> 1) & 3;
        int hl = (frag >> 3) & 1;
        int mat = (frag >> 4) & 1;
        const float* W = mat ? Wr : Wl;
        int j = (lane & 15) + 16 * ct;
        int d0 = (lane >> 4) * 8 + 32 * kh;
        ushort o[8];
#pragma unroll
        for (int i = 0; i < 8; ++i) {
            float v = W[j * 64 + d0 + i];
            ushort hi = f32_to_bf16_rne(v);
            if (hl == 0) {
                o[i] = hi;
            } else {
                float r = v - __uint_as_float(((unsigned)hi) << 16);
                o[i] = f32_to_bf16_rne(r);
            }
        }
        bf16x8 w;
#pragma unroll
        for (int i = 0; i < 8; ++i) w[i] = (short)o[i];
        *(bf16x8*)&packed[(size_t)t * 8] = w;
    } else {
        // ---- x -> bf16 ----
        long long i = (long long)(bid - hb - 8) * 256 + threadIdx.x;
        if (i < M8) {
            float4 v0 = ((const float4*)x)[i * 2];
            float4 v1 = ((const float4*)x)[i * 2 + 1];
            ushort8 h;
            h[0] = f32_to_bf16_rne(v0.x); h[1] = f32_to_bf16_rne(v0.y);
            h[2] = f32_to_bf16_rne(v0.z); h[3] = f32_to_bf16_rne(v0.w);
            h[4] = f32_to_bf16_rne(v1.x); h[5] = f32_to_bf16_rne(v1.y);
            h[6] = f32_to_bf16_rne(v1.z); h[7] = f32_to_bf16_rne(v1.w);
            *(ushort8*)&xh[i * 8] = h;
        }
    }
}

// ---- B: exclusive scan of bucket counts -> bucket base + cursor ----
__global__ __launch_bounds__(1024) void bucket_scan_kernel(
        const int* __restrict__ gh, int* __restrict__ bbase,
        int* __restrict__ gcur, int NB, int E) {
    __shared__ int lds[MAXNB];
    int t = threadIdx.x;
    int v = (t < NB) ? gh[t] : 0;
    lds[t] = v;
    __syncthreads();
    for (int off = 1; off < 1024; off <<= 1) {
        int u = (t >= off) ? lds[t - off] : 0;
        __syncthreads();
        lds[t] += u;
        __syncthreads();
    }
    if (t < NB) {
        int b = lds[t] - v;        // exclusive
        bbase[t] = b;
        gcur[t] = b;
    }
    if (t == 0) bbase[NB] = E;
}

// ---- C: bin edges into bucket-contiguous regions as packed words ----
__global__ __launch_bounds__(1024) void bucket_fill_kernel(
        const int* __restrict__ ei, int* __restrict__ gcur,
        unsigned* __restrict__ pairs, int E, int N, int NB) {
    __shared__ int ldsh[MAXNB];
    for (int t = threadIdx.x; t < NB; t += 1024) ldsh[t] = 0;
    __syncthreads();
    int base = blockIdx.x * (1024 * EPT);
    int lofs[EPT];
#pragma unroll
    for (int i = 0; i < EPT; ++i) {
        int e = base + threadIdx.x + i * 1024;
        if (e < E) {
            int dst = ei[E + e];
            dst = min(max(dst, 0), N - 1);
            lofs[i] = atomicAdd(&ldsh[dst >> BSH], 1);
        }
    }
    __syncthreads();
    for (int t = threadIdx.x; t < NB; t += 1024) {
        int c = ldsh[t];
        int run = c ? atomicAdd(&gcur[t], c) : 0;
        ldsh[t] = run;
    }
    __syncthreads();
#pragma unroll
    for (int i = 0; i < EPT; ++i) {
        int e = base + threadIdx.x + i * 1024;
        if (e < E) {
            int src = ei[e];
            int dst = ei[E + e];
            src = min(max(src, 0), N - 1);
            dst = min(max(dst, 0), N - 1);
            int b = dst >> BSH;
            unsigned w = ((unsigned)src << BSH) | (unsigned)(dst & (BW - 1));
            pairs[ldsh[b] + lofs[i]] = w;
        }
    }
}

// ---- D: per-sub-bucket sort + register gather (256 thr, 4 waves, 32 nodes)
// blockIdx = bucket*4 + sub. Stage bucket pairs window in LDS once; filter to
// this sub-block's 32 nodes; sort into srcl; gather-accumulate in VGPRs.
__global__ __launch_bounds__(256) void aggregate_kernel(
        const ushort* __restrict__ xh, const unsigned* __restrict__ pairs,
        const int* __restrict__ bbase, float* __restrict__ mean_out, int N) {
    __shared__ unsigned plds[AGG_WIN];
    __shared__ int srcl[AGG_WIN];
    __shared__ int cnt[NPB];
    __shared__ int noff[NPB + 1];
    const int b = blockIdx.x >> 2;
    const int lo = (blockIdx.x & 3) * NPB;    // local node range [lo, lo+32)
    const int tid = threadIdx.x;
    const int lane = tid & 63;
    const int wv = tid >> 6;                  // 0..3
    const int slot = lane >> 4;               // 0..3
    const int l16 = lane & 15;
    const int e0 = bbase[b], e1 = bbase[b + 1];

    float4 acc[8];
    int degt[8];
#pragma unroll
    for (int k = 0; k < 8; ++k) {
        acc[k] = make_float4(0.f, 0.f, 0.f, 0.f);
        degt[k] = 0;
    }

    for (int c0 = e0; c0 < e1; c0 += AGG_WIN) {
        const int C = min(AGG_WIN, e1 - c0);
        // stage pairs window (single global read)
        for (int i = tid; i < C; i += 256) plds[i] = pairs[c0 + i];
        if (tid < NPB) cnt[tid] = 0;
        __syncthreads();
        // count filtered
        for (int i = tid; i < C; i += 256) {
            int lr = (int)(plds[i] & (BW - 1)) - lo;
            if ((unsigned)lr < (unsigned)NPB) atomicAdd(&cnt[lr], 1);
        }
        __syncthreads();
        // exclusive scan of 32 counters (wave 0)
        if (tid < 64) {
            int c = (lane < NPB) ? cnt[lane] : 0;
            int a = c;
            for (int off = 1; off < NPB; off <<= 1) {
                int u = __shfl_up(a, off, 64);
                if (lane >= off) a += u;
            }
            if (lane < NPB) noff[lane] = a - c;
            if (lane == NPB - 1) noff[NPB] = a;
        }
        __syncthreads();
        if (tid < NPB) cnt[tid] = 0;
        __syncthreads();
        // scatter src into node-sorted LDS order
        for (int i = tid; i < C; i += 256) {
            unsigned w = plds[i];
            int lr = (int)(w & (BW - 1)) - lo;
            if ((unsigned)lr < (unsigned)NPB) {
                int p = noff[lr] + atomicAdd(&cnt[lr], 1);
                srcl[p] = (int)(w >> BSH);
            }
        }
        __syncthreads();
        // gather + accumulate: wave wv owns nodes lo + wv*8 + k
#pragma unroll
        for (int k = 0; k < 8; ++k) {
            int lr = wv * 8 + k;
            int r0 = noff[lr], r1 = noff[lr + 1];
            degt[k] += r1 - r0;
            for (int e = r0 + slot; e < r1; e += 4) {
                int src = srcl[e];
                ushort4 h = *(const ushort4*)&xh[(size_t)src * D + l16 * 4];
                acc[k].x += bf16_to_f32(h.x);
                acc[k].y += bf16_to_f32(h.y);
                acc[k].z += bf16_to_f32(h.z);
                acc[k].w += bf16_to_f32(h.w);
            }
        }
        __syncthreads();
    }
    // reduce across 4 edge-slots, write mean
    const int nodebase = (b << BSH) + lo;
#pragma unroll
    for (int k = 0; k < 8; ++k) {
        acc[k].x += __shfl_xor(acc[k].x, 16, 64);
        acc[k].y += __shfl_xor(acc[k].y, 16, 64);
        acc[k].z += __shfl_xor(acc[k].z, 16, 64);
        acc[k].w += __shfl_xor(acc[k].w, 16, 64);
        acc[k].x += __shfl_xor(acc[k].x, 32, 64);
        acc[k].y += __shfl_xor(acc[k].y, 32, 64);
        acc[k].z += __shfl_xor(acc[k].z, 32, 64);
        acc[k].w += __shfl_xor(acc[k].w, 32, 64);
        if (slot == 0) {
            int node = nodebase + wv * 8 + k;
            if (node < N) {
                float inv = 1.0f / fmaxf((float)degt[k], 1.0f);
                float4 m;
                m.x = acc[k].x * inv; m.y = acc[k].y * inv;
                m.z = acc[k].z * inv; m.w = acc[k].w * inv;
                *(float4*)&mean_out[(size_t)node * D + l16 * 4] = m;
            }
        }
    }
}

// ---- MFMA linear: out = mean @ Wl^T + b + x @ Wr^T (+ stats) ----
__global__ __launch_bounds__(256, 2) void linear_mfma_kernel(
        const float* __restrict__ x, const ushort* __restrict__ packed,
        const float* __restrict__ bl, float* out, float* stats, int G, int N) {
    const int lane = threadIdx.x & 63;
    const int wid = blockIdx.x * (blockDim.x >> 6) + (threadIdx.x >> 6);
    const int nwaves = gridDim.x * (blockDim.x >> 6);
    const int r16 = lane & 15;
    const int kblk = lane >> 4;

    bf16x8 bfrag[2][2][4][2];   // [mat][hl][ct][kh]
#pragma unroll
    for (int mat = 0; mat < 2; ++mat)
#pragma unroll
        for (int hl = 0; hl < 2; ++hl)
#pragma unroll
            for (int ct = 0; ct < 4; ++ct)
#pragma unroll
                for (int kh = 0; kh < 2; ++kh) {
                    int frag = mat * 16 + hl * 8 + ct * 2 + kh;
                    bfrag[mat][hl][ct][kh] =
                        *(const bf16x8*)&packed[((size_t)frag * 64 + lane) * 8];
                }
    float blv[4];
#pragma unroll
    for (int ct = 0; ct < 4; ++ct) blv[ct] = bl[16 * ct + r16];

    float ls = 0.0f, lsq = 0.0f;
    for (int g = wid; g < G; g += nwaves) {
        int rowbase = g * 16;
        int arow = min(rowbase + r16, N - 1);
        bf16x8 ahi[2][2], alo[2][2];
#pragma unroll
        for (int mat = 0; mat < 2; ++mat) {
            const float* src = mat ? x : out;
#pragma unroll
            for (int kh = 0; kh < 2; ++kh) {
                const float* p = &src[(size_t)arow * D + kblk * 8 + kh * 32];
                float4 v0 = *(const float4*)p;
                float4 v1 = *(const float4*)(p + 4);
                float vv[8] = {v0.x, v0.y, v0.z, v0.w, v1.x, v1.y, v1.z, v1.w};
                bf16x8 h, l;
#pragma unroll
                for (int i = 0; i < 8; ++i) {
                    ushort hu = f32_to_bf16_rne(vv[i]);
                    h[i] = (short)hu;
                    float r = vv[i] - __uint_as_float(((unsigned)hu) << 16);
                    l[i] = (short)f32_to_bf16_rne(r);
                }
                ahi[mat][kh] = h;
                alo[mat][kh] = l;
            }
        }
        f32x4 acc[4];
#pragma unroll
        for (int ct = 0; ct < 4; ++ct) acc[ct] = (f32x4)(0.0f);
#pragma unroll
        for (int ct = 0; ct < 4; ++ct)
#pragma unroll
            for (int mat = 0; mat < 2; ++mat)
#pragma unroll
                for (int kh = 0; kh < 2; ++kh) {
                    acc[ct] = __builtin_amdgcn_mfma_f32_16x16x32_bf16(
                        ahi[mat][kh], bfrag[mat][0][ct][kh], acc[ct], 0, 0, 0);
                    acc[ct] = __builtin_amdgcn_mfma_f32_16x16x32_bf16(
                        ahi[mat][kh], bfrag[mat][1][ct][kh], acc[ct], 0, 0, 0);
                    acc[ct] = __builtin_amdgcn_mfma_f32_16x16x32_bf16(
                        alo[mat][kh], bfrag[mat][0][ct][kh], acc[ct], 0, 0, 0);
                }
#pragma unroll
        for (int ct = 0; ct < 4; ++ct) {
#pragma unroll
            for (int r = 0; r < 4; ++r) {
                int row = rowbase + kblk * 4 + r;
                if (row < N) {
                    float v = acc[ct][r] + blv[ct];
                    out[(size_t)row * D + 16 * ct + r16] = v;
                    ls += v;
                    lsq += v * v;
                }
            }
        }
    }
    for (int off = 32; off > 0; off >>= 1) {
        ls += __shfl_down(ls, off, 64);
        lsq += __shfl_down(lsq, off, 64);
    }
    if (lane == 0) {
        atomicAdd(&stats[0], ls);
        atomicAdd(&stats[1], lsq);
    }
}

// ---- in-place graph layernorm on d_out ----
__global__ void norm_kernel(const float* __restrict__ stats,
                            const float* __restrict__ lw,
                            const float* __restrict__ lb,
                            float* out, long long M4) {
    long long i = (long long)blockIdx.x * blockDim.x + threadIdx.x;
    if (i >= M4) return;
    const float inv_M = 1.0f / (float)(M4 * 4);
    float mu = stats[0] * inv_M;
    float var = stats[1] * inv_M - mu * mu;
    float rs = 1.0f / sqrtf(var + EPS);
    float4 v = ((const float4*)out)[i];
    int col = (int)((i * 4) & (D - 1));
    float4 w = *(const float4*)&lw[col];
    float4 b = *(const float4*)&lb[col];
    v.x = (v.x - mu) * rs * w.x + b.x;
    v.y = (v.y - mu) * rs * w.y + b.y;
    v.z = (v.z - mu) * rs * w.z + b.z;
    v.w = (v.w - mu) * rs * w.w + b.w;
    ((float4*)out)[i] = v;
}

extern "C" void kernel_launch(void* const* d_in, const int* in_sizes, int n_in,
                              void* d_out, int out_size, void* d_ws, size_t ws_size,
                              hipStream_t stream) {
    const float* x  = (const float*)d_in[0];
    const int*   ei = (const int*)d_in[1];
    const float* Wl = (const float*)d_in[2];
    const float* bl = (const float*)d_in[3];
    const float* Wr = (const float*)d_in[4];
    const float* lw = (const float*)d_in[5];
    const float* lb = (const float*)d_in[6];
    float* out = (float*)d_out;

    const int N = in_sizes[0] / D;       // 100000
    const int E = in_sizes[1] / 2;       // 1200000
    const int NB = (N + BW - 1) >> BSH;  // 782

    // ws: stats(2f) | gh(1024) | bbase(1025) | gcur(1024) | pairs(E u32) |
    //     packedw(2048*8 u16) | xh(N*64 u16)
    float* stats    = (float*)d_ws;
    int* gh         = (int*)d_ws + 2;
    int* bbase      = gh + MAXNB;
    int* gcur       = bbase + (MAXNB + 1);
    unsigned* pairs = (unsigned*)(gcur + MAXNB);
    ushort* packedw = (ushort*)(pairs + E);
    ushort* xh      = packedw + 2048 * 8;

    hipMemsetAsync(d_ws, 0, (size_t)(2 + MAXNB) * sizeof(int), stream);

    long long M8 = (long long)N * D / 8;              // 800000
    int hb = (E + 256 * EPT_H - 1) / (256 * EPT_H);   // 293
    int xb = (int)((M8 + 255) / 256);                 // 3125
    prep_kernel<<<hb + 8 + xb, 256, 0, stream>>>(x, xh, M8, ei, gh, E, N, NB,
                                                 hb, Wl, Wr, packedw);

    bucket_scan_kernel<<<1, 1024, 0, stream>>>(gh, bbase, gcur, NB, E);

    int eb = (E + 1024 * EPT - 1) / (1024 * EPT);     // 98
    bucket_fill_kernel<<<eb, 1024, 0, stream>>>(ei, gcur, pairs, E, N, NB);

    aggregate_kernel<<<NB * 4, 256, 0, stream>>>(xh, pairs, bbase, out, N);

    int G = (N + 15) / 16;   // 6250
    linear_mfma_kernel<<<512, 256, 0, stream>>>(x, packedw, bl, out, stats, G, N);

    long long M4 = (long long)N * D / 4;
    int blocks4 = (int)((M4 + 255) / 256);
    norm_kernel<<<blocks4, 256, 0, stream>>>(stats, lw, lb, out, M4);
}